// Round 4
// baseline (105.139 us; speedup 1.0000x reference)
//
#include <hip/hip_runtime.h>
#include <stdint.h>

typedef unsigned short u16;
typedef __attribute__((ext_vector_type(4))) float f32x4;
typedef __attribute__((ext_vector_type(2))) float f32x2;
typedef __attribute__((ext_vector_type(8))) short s16x8;

#define T_INV 10.0f

__device__ __forceinline__ u16 f2bf(float f) {
  uint32_t u = __float_as_uint(f);
  uint32_t r = (u + 0x7FFFu + ((u >> 16) & 1u)) >> 16;
  return (u16)r;
}

__device__ __forceinline__ void gload_lds16(const void* g, void* l) {
  __builtin_amdgcn_global_load_lds(
      (const __attribute__((address_space(1))) uint32_t*)(g),
      (__attribute__((address_space(3))) uint32_t*)(l),
      16, 0, 0);
}

// ---------------- kernel 1: per-row softmax tables ----------------
// plo[b][lo]  = prod_{f=4..7} hot[f][digit]      (bf16, [1024][256])
// phiT[hi][b] = prod_{f=0..3} hot[f][digit]      (f32, [256][1024], TRANSPOSED)
__global__ __launch_bounds__(256) void k_tables(
    const float* __restrict__ x, const float* __restrict__ beta,
    u16* __restrict__ plo, float* __restrict__ phiT)
{
  const int t = threadIdx.x;
  const int b = blockIdx.x * 64 + (t >> 2);
  const int q = t & 3;

  float hot[8][4];
#pragma unroll
  for (int f = 0; f < 8; ++f) {
    float b0 = beta[f*3+0], b1 = beta[f*3+1], b2 = beta[f*3+2];
    float s0 = fminf(b0, fminf(b1, b2));
    float s2 = fmaxf(b0, fmaxf(b1, b2));
    float s1 = b0 + b1 + b2 - s0 - s2;
    float bv1 = -s0, bv2 = -(s0 + s1), bv3 = -(s0 + s1 + s2);
    float xf = x[b*8 + f];
    float l0 = (xf * 1.0f       ) * T_INV;
    float l1 = (xf * 2.0f + bv1) * T_INV;
    float l2 = (xf * 3.0f + bv2) * T_INV;
    float l3 = (xf * 4.0f + bv3) * T_INV;
    float mm = fmaxf(fmaxf(l0, l1), fmaxf(l2, l3));
    float e0 = __expf(l0 - mm), e1 = __expf(l1 - mm);
    float e2 = __expf(l2 - mm), e3 = __expf(l3 - mm);
    float inv = 1.0f / (e0 + e1 + e2 + e3);
    hot[f][0] = e0*inv; hot[f][1] = e1*inv; hot[f][2] = e2*inv; hot[f][3] = e3*inv;
  }

  {
    float h23[16];
#pragma unroll
    for (int i2 = 0; i2 < 4; ++i2)
#pragma unroll
      for (int i3 = 0; i3 < 4; ++i3) h23[i2*4+i3] = hot[2][i2] * hot[3][i3];
    float h0q = hot[0][q];
#pragma unroll
    for (int i1 = 0; i1 < 4; ++i1) {
      float c01 = h0q * hot[1][i1];
#pragma unroll
      for (int j = 0; j < 16; ++j)
        phiT[(size_t)(q*64 + i1*16 + j) * 1024 + b] = c01 * h23[j];
    }
  }
  {
    float h67[16];
#pragma unroll
    for (int i6 = 0; i6 < 4; ++i6)
#pragma unroll
      for (int i7 = 0; i7 < 4; ++i7) h67[i6*4+i7] = hot[6][i6] * hot[7][i7];
    float h4q = hot[4][q];
    u16* dst = plo + (size_t)b*256 + q*64;
#pragma unroll
    for (int i5 = 0; i5 < 4; ++i5) {
      float c45 = h4q * hot[5][i5];
#pragma unroll
      for (int j = 0; j < 16; j += 8) {
        s16x8 v;
#pragma unroll
        for (int e = 0; e < 8; ++e) v[e] = (short)f2bf(c45 * h67[j+e]);
        *(s16x8*)(dst + i5*16 + j) = v;
      }
    }
  }
}

// ---------------- kernel 1b: classifier fp32 [65536][128] -> bf16 CT3 ----------------
// CT3 element (k, c) lives at u16 offset (k>>3)*1024 + c*8 + (k&7)
// (fragment-major: each MFMA B-fragment = 16 contiguous bytes)
__global__ __launch_bounds__(256) void k_transpose(
    const float* __restrict__ cls, u16* __restrict__ ct)
{
  __shared__ float tile[64 * 132];
  const int t = threadIdx.x;
  const int k0 = blockIdx.x * 64;
#pragma unroll
  for (int it = 0; it < 8; ++it) {
    int e = it * 1024 + t * 4;
    int r = e >> 7;
    int c = e & 127;
    f32x4 v = *(const f32x4*)(cls + (size_t)(k0 + r) * 128 + c);
    *(f32x4*)(tile + r * 132 + c) = v;
  }
  __syncthreads();
  const int c  = t >> 1;
  const int kh = t & 1;
  u16 vals[32];
#pragma unroll
  for (int j = 0; j < 32; ++j)
    vals[j] = f2bf(tile[(kh*32 + j) * 132 + c]);
  u16* dst = ct + ((size_t)(k0 >> 3) + kh * 4) * 1024 + c * 8;
#pragma unroll
  for (int qq = 0; qq < 4; ++qq) {
    s16x8 v;
#pragma unroll
    for (int e2 = 0; e2 < 8; ++e2) v[e2] = (short)vals[qq*8 + e2];
    *(s16x8*)(dst + (size_t)qq * 1024) = v;
  }
}

// ---------------- main kernel ----------------
// grid 512 = 8 m-tiles (128 rows) x 64 hi-groups (4 his, K-chunk 1024)
// 512 threads / 8 waves; wave tile 64 rows x 32 cols of 16x16x32 bf16 MFMA
// A (P_lo) static in LDS (one barrier total); B direct global->register (L2).
// NO barriers in the K-loop.
__global__ __launch_bounds__(512, 4) void k_main(
    const u16* __restrict__ plo, const float* __restrict__ phiT,
    const u16* __restrict__ ct, u16* __restrict__ pws)
{
  __shared__ __align__(16) u16 As[8][4096];   // [ks][row*32 + slot*8]  64KB static

  const int wg  = blockIdx.x;
  const int xcd = wg & 7;
  const int idx = wg >> 3;
  const int hig = xcd * 8 + (idx >> 3);   // all 8 m-tiles of a hi-group on one XCD
  const int m   = idx & 7;

  const int t    = threadIdx.x;
  const int l    = t & 63;
  const int w    = t >> 6;
  const int lrow = l & 15;
  const int kg   = l >> 4;
  const int rbase = (w & 1) * 64;
  const int cbase = (w >> 1) * 32;

  const u16* ploM = plo + (size_t)m * 128 * 256;
  const int srow = t >> 2;
  const int ssl  = t & 3;
  const int sg   = (ssl - ((srow >> 1) & 3)) & 3;   // granule staged into this slot

  // ---- prologue: stage all of A (8 k-chunks) ----
#pragma unroll
  for (int ks = 0; ks < 8; ++ks)
    gload_lds16(ploM + (size_t)srow * 256 + ks * 32 + sg * 8, &As[ks][t * 8]);
  __syncthreads();

  // per-lane fragment bases
  const int s_a = (kg + ((lrow >> 1) & 3)) & 3;
  const u16* aP = &As[0][0] + (rbase + lrow) * 32 + s_a * 8;
  const u16* bP = ct + (size_t)hig * 131072 + (size_t)kg * 1024
                     + (size_t)(cbase + lrow) * 8;

  f32x4 acc[4][2], hacc[4][2];
#pragma unroll
  for (int i = 0; i < 4; ++i)
#pragma unroll
    for (int j = 0; j < 2; ++j) { acc[i][j] = (f32x4)0.0f; hacc[i][j] = (f32x4)0.0f; }

#pragma unroll 1
  for (int h = 0; h < 4; ++h) {
    const u16* bh = bP + (size_t)h * 32768;
#pragma unroll
    for (int ks = 0; ks < 8; ++ks) {
      s16x8 afr[4], bfr[2];
#pragma unroll
      for (int nt = 0; nt < 2; ++nt)
        bfr[nt] = *(const s16x8*)(bh + ks * 4096 + nt * 128);
#pragma unroll
      for (int mt = 0; mt < 4; ++mt)
        afr[mt] = *(const s16x8*)(aP + ks * 4096 + mt * 512);
#pragma unroll
      for (int mt = 0; mt < 4; ++mt)
#pragma unroll
        for (int nt = 0; nt < 2; ++nt)
          hacc[mt][nt] = __builtin_amdgcn_mfma_f32_16x16x32_bf16(
              afr[mt], bfr[nt], hacc[mt][nt], 0, 0, 0);
    }
    // fold hi h: acc += phiT[hig*4+h][m*128+row] * hacc  (f32x4 L2 loads)
    const float* ph = phiT + (size_t)(hig * 4 + h) * 1024 + m * 128;
#pragma unroll
    for (int mt = 0; mt < 4; ++mt) {
      f32x4 p4 = *(const f32x4*)(ph + rbase + mt * 16 + kg * 4);
#pragma unroll
      for (int r = 0; r < 4; ++r) {
#pragma unroll
        for (int nt = 0; nt < 2; ++nt)
          acc[mt][nt][r] += p4[r] * hacc[mt][nt][r];
      }
#pragma unroll
      for (int nt = 0; nt < 2; ++nt) hacc[mt][nt] = (f32x4)0.0f;
    }
  }

  // epilogue: bf16 partial store, P[hig][1024][128]
  u16* dst = pws + ((size_t)hig * 1024 + (size_t)m * 128) * 128;
#pragma unroll
  for (int mt = 0; mt < 4; ++mt)
#pragma unroll
    for (int r = 0; r < 4; ++r) {
      int row = rbase + mt * 16 + kg * 4 + r;
#pragma unroll
      for (int nt = 0; nt < 2; ++nt) {
        int col = cbase + nt * 16 + lrow;
        dst[row * 128 + col] = f2bf(acc[mt][nt][r]);
      }
    }
}

// ---------------- reduce: out[e] = sum_hig P[hig][e] ----------------
__global__ __launch_bounds__(256) void k_reduce(
    const u16* __restrict__ p, float* __restrict__ out)
{
  const int g = blockIdx.x * 256 + threadIdx.x;   // 0..65535, 2 elems each
  const u16* src = p + (size_t)g * 2;
  float a0 = 0.0f, a1 = 0.0f;
#pragma unroll 8
  for (int hig = 0; hig < 64; ++hig) {
    uint32_t v = *(const uint32_t*)(src + (size_t)hig * 131072);
    a0 += __uint_as_float((v & 0xFFFFu) << 16);
    a1 += __uint_as_float(v & 0xFFFF0000u);
  }
  f32x2 o; o.x = a0; o.y = a1;
  *(f32x2*)(out + (size_t)g * 2) = o;
}

extern "C" void kernel_launch(void* const* d_in, const int* in_sizes, int n_in,
                              void* d_out, int out_size, void* d_ws, size_t ws_size,
                              hipStream_t stream)
{
  const float* x    = (const float*)d_in[0];
  const float* beta = (const float*)d_in[1];
  const float* cls  = (const float*)d_in[2];
  float* out = (float*)d_out;

  char* ws = (char*)d_ws;
  u16*   ct   = (u16*)ws;                               // 16,777,216 B
  u16*   plo  = (u16*)(ws + (16u << 20));               //    524,288 B
  float* phiT = (float*)(ws + (16u << 20) + 524288);    //  1,048,576 B
  u16*   pws  = (u16*)(ws + (16u << 20) + 524288 + 1048576); // 16,777,216 B

  k_tables<<<16, 256, 0, stream>>>(x, beta, plo, phiT);
  k_transpose<<<1024, 256, 0, stream>>>(cls, ct);
  k_main<<<512, 512, 0, stream>>>(plo, phiT, ct, pws);
  k_reduce<<<256, 256, 0, stream>>>(pws, out);
}

// Round 5
// 53.972 us; speedup vs baseline: 1.9480x; 1.9480x over previous
//
#include <hip/hip_runtime.h>
#include <stdint.h>

typedef unsigned short u16;
typedef __attribute__((ext_vector_type(4))) float f32x4;
typedef __attribute__((ext_vector_type(2))) float f32x2;
typedef __attribute__((ext_vector_type(8))) short s16x8;

#define T_INV 10.0f

__device__ __forceinline__ u16 f2bf(float f) {
  uint32_t u = __float_as_uint(f);
  uint32_t r = (u + 0x7FFFu + ((u >> 16) & 1u)) >> 16;
  return (u16)r;
}

__device__ __forceinline__ void gload_lds16(const void* g, void* l) {
  __builtin_amdgcn_global_load_lds(
      (const __attribute__((address_space(1))) uint32_t*)(g),
      (__attribute__((address_space(3))) uint32_t*)(l),
      16, 0, 0);
}

// ---------------- kernel 1: per-row softmax tables ----------------
// plo[b][lo]  = prod_{f=4..7} hot[f][digit]      (bf16, [1024][256])
// phiT[hi][b] = prod_{f=0..3} hot[f][digit]      (f32, [256][1024], TRANSPOSED)
__global__ __launch_bounds__(256) void k_tables(
    const float* __restrict__ x, const float* __restrict__ beta,
    u16* __restrict__ plo, float* __restrict__ phiT)
{
  const int t = threadIdx.x;
  const int b = blockIdx.x * 64 + (t >> 2);
  const int q = t & 3;

  float hot[8][4];
#pragma unroll
  for (int f = 0; f < 8; ++f) {
    float b0 = beta[f*3+0], b1 = beta[f*3+1], b2 = beta[f*3+2];
    float s0 = fminf(b0, fminf(b1, b2));
    float s2 = fmaxf(b0, fmaxf(b1, b2));
    float s1 = b0 + b1 + b2 - s0 - s2;
    float bv1 = -s0, bv2 = -(s0 + s1), bv3 = -(s0 + s1 + s2);
    float xf = x[b*8 + f];
    float l0 = (xf * 1.0f       ) * T_INV;
    float l1 = (xf * 2.0f + bv1) * T_INV;
    float l2 = (xf * 3.0f + bv2) * T_INV;
    float l3 = (xf * 4.0f + bv3) * T_INV;
    float mm = fmaxf(fmaxf(l0, l1), fmaxf(l2, l3));
    float e0 = __expf(l0 - mm), e1 = __expf(l1 - mm);
    float e2 = __expf(l2 - mm), e3 = __expf(l3 - mm);
    float inv = 1.0f / (e0 + e1 + e2 + e3);
    hot[f][0] = e0*inv; hot[f][1] = e1*inv; hot[f][2] = e2*inv; hot[f][3] = e3*inv;
  }

  {
    float h23[16];
#pragma unroll
    for (int i2 = 0; i2 < 4; ++i2)
#pragma unroll
      for (int i3 = 0; i3 < 4; ++i3) h23[i2*4+i3] = hot[2][i2] * hot[3][i3];
    float h0q = hot[0][q];
#pragma unroll
    for (int i1 = 0; i1 < 4; ++i1) {
      float c01 = h0q * hot[1][i1];
#pragma unroll
      for (int j = 0; j < 16; ++j)
        phiT[(size_t)(q*64 + i1*16 + j) * 1024 + b] = c01 * h23[j];
    }
  }
  {
    float h67[16];
#pragma unroll
    for (int i6 = 0; i6 < 4; ++i6)
#pragma unroll
      for (int i7 = 0; i7 < 4; ++i7) h67[i6*4+i7] = hot[6][i6] * hot[7][i7];
    float h4q = hot[4][q];
    u16* dst = plo + (size_t)b*256 + q*64;
#pragma unroll
    for (int i5 = 0; i5 < 4; ++i5) {
      float c45 = h4q * hot[5][i5];
#pragma unroll
      for (int j = 0; j < 16; j += 8) {
        s16x8 v;
#pragma unroll
        for (int e = 0; e < 8; ++e) v[e] = (short)f2bf(c45 * h67[j+e]);
        *(s16x8*)(dst + i5*16 + j) = v;
      }
    }
  }
}

// ---------------- kernel 1b: classifier fp32 [65536][128] -> bf16 CT [128][65536] ----------------
__global__ __launch_bounds__(256) void k_transpose(
    const float* __restrict__ cls, u16* __restrict__ ct)
{
  __shared__ float tile[64 * 132];
  const int t = threadIdx.x;
  const int k0 = blockIdx.x * 64;
#pragma unroll
  for (int it = 0; it < 8; ++it) {
    int e = it * 1024 + t * 4;
    int r = e >> 7;
    int c = e & 127;
    f32x4 v = *(const f32x4*)(cls + (size_t)(k0 + r) * 128 + c);
    *(f32x4*)(tile + r * 132 + c) = v;
  }
  __syncthreads();
  const int c  = t >> 1;
  const int kh = t & 1;
  u16 vals[32];
#pragma unroll
  for (int j = 0; j < 32; ++j)
    vals[j] = f2bf(tile[(kh*32 + j) * 132 + c]);
  u16* dst = ct + (size_t)c * 65536 + k0 + kh * 32;
#pragma unroll
  for (int qq = 0; qq < 4; ++qq) {
    s16x8 v;
#pragma unroll
    for (int e2 = 0; e2 < 8; ++e2) v[e2] = (short)vals[qq*8 + e2];
    *(s16x8*)(dst + qq*8) = v;
  }
}

// ---------------- main kernel ----------------
// grid 512 = 8 m-tiles (128 rows) x 64 hi-groups (4 his, K-chunk 1024)
// 512 threads / 8 waves; wave tile 64 rows x 32 cols of 16x16x32 bf16 MFMA
// A (P_lo) static in LDS; B double-buffered via global_load_lds with
// COUNTED vmcnt(1) + raw barriers (stage t+1 stays in flight across barriers).
__global__ __launch_bounds__(512, 4) void k_main(
    const u16* __restrict__ plo, const float* __restrict__ phiT,
    const u16* __restrict__ ct, u16* __restrict__ pws)
{
  __shared__ __align__(16) u16 As[8][4096];   // [ks][row*32 + slot*8]  64KB
  __shared__ __align__(16) u16 Bb[2][4096];   // [buf][col*32 + slot*8] 16KB

  const int wg  = blockIdx.x;
  const int xcd = wg & 7;
  const int idx = wg >> 3;
  const int hig = xcd * 8 + (idx >> 3);   // all 8 m-tiles of a hi-group on one XCD
  const int m   = idx & 7;

  const int t    = threadIdx.x;
  const int l    = t & 63;
  const int w    = t >> 6;
  const int lrow = l & 15;
  const int kg   = l >> 4;
  const int rbase = (w & 1) * 64;
  const int cbase = (w >> 1) * 32;

  const u16* ploM = plo + (size_t)m * 128 * 256;
  const int srow = t >> 2;
  const int ssl  = t & 3;
  const int sg   = (ssl - ((srow >> 1) & 3)) & 3;   // granule staged into this slot

  auto stageB = [&](int h, int ks, int buf) {
    int k0 = (hig * 4 + h) * 256 + ks * 32;
    gload_lds16(ct + (size_t)srow * 65536 + k0 + sg * 8, &Bb[buf][t * 8]);
  };

  // ---- prologue: stage all of A (8 k-chunks) + B0; full drain once ----
#pragma unroll
  for (int ks = 0; ks < 8; ++ks)
    gload_lds16(ploM + (size_t)srow * 256 + ks * 32 + sg * 8, &As[ks][t * 8]);
  stageB(0, 0, 0);
  asm volatile("s_waitcnt vmcnt(0)" ::: "memory");
  __builtin_amdgcn_s_barrier();
  __builtin_amdgcn_sched_barrier(0);

  f32x4 acc[4][2], hacc[4][2];
#pragma unroll
  for (int i = 0; i < 4; ++i)
#pragma unroll
    for (int j = 0; j < 2; ++j) { acc[i][j] = (f32x4)0.0f; hacc[i][j] = (f32x4)0.0f; }

#pragma unroll 1
  for (int h = 0; h < 4; ++h) {
#pragma unroll
    for (int ks = 0; ks < 8; ++ks) {
      const int buf = ks & 1;          // (h*8+ks)&1 == ks&1
      if (h < 3 || ks < 7) {
        int nks = (ks + 1) & 7;
        int nh  = h + (ks == 7);
        stageB(nh, nks, buf ^ 1);      // stage t+1, kept in flight
      }
      asm volatile("s_waitcnt vmcnt(1)" ::: "memory");   // stage t complete
      __builtin_amdgcn_sched_barrier(0);
      __builtin_amdgcn_s_barrier();                      // barrier_A
      __builtin_amdgcn_sched_barrier(0);

      s16x8 afr[4], bfr[2];
#pragma unroll
      for (int mt = 0; mt < 4; ++mt) {
        int row = rbase + mt * 16 + lrow;
        int s = (kg + ((row >> 1) & 3)) & 3;
        afr[mt] = *(const s16x8*)&As[ks][row * 32 + s * 8];
      }
#pragma unroll
      for (int nt = 0; nt < 2; ++nt) {
        int c = cbase + nt * 16 + lrow;
        int s = (kg + ((c >> 1) & 3)) & 3;
        bfr[nt] = *(const s16x8*)&Bb[buf][c * 32 + s * 8];
      }
#pragma unroll
      for (int mt = 0; mt < 4; ++mt)
#pragma unroll
        for (int nt = 0; nt < 2; ++nt)
          hacc[mt][nt] = __builtin_amdgcn_mfma_f32_16x16x32_bf16(
              afr[mt], bfr[nt], hacc[mt][nt], 0, 0, 0);

      __builtin_amdgcn_sched_barrier(0);
      __builtin_amdgcn_s_barrier();                      // barrier_B (no vmcnt!)
      __builtin_amdgcn_sched_barrier(0);
    }
    // fold hi h: acc += phiT[hig*4+h][m*128+row] * hacc  (f32x4 L2 loads)
    const float* ph = phiT + (size_t)(hig * 4 + h) * 1024 + m * 128;
#pragma unroll
    for (int mt = 0; mt < 4; ++mt) {
      f32x4 p4 = *(const f32x4*)(ph + rbase + mt * 16 + kg * 4);
#pragma unroll
      for (int r = 0; r < 4; ++r) {
#pragma unroll
        for (int nt = 0; nt < 2; ++nt)
          acc[mt][nt][r] += p4[r] * hacc[mt][nt][r];
      }
#pragma unroll
      for (int nt = 0; nt < 2; ++nt) hacc[mt][nt] = (f32x4)0.0f;
    }
  }

  // ---- epilogue: bounce through LDS (reuse As), then coalesced 16B stores ----
  // LDS layout: [128 rows][144 u16] (pad 144 breaks bank alignment of 256B rows)
  {
    u16* ob = (u16*)&As[0][0];   // 128*144*2 = 36864 B <= 64KB
#pragma unroll
    for (int mt = 0; mt < 4; ++mt)
#pragma unroll
      for (int r = 0; r < 4; ++r) {
        int row = rbase + mt * 16 + kg * 4 + r;
#pragma unroll
        for (int nt = 0; nt < 2; ++nt) {
          int col = cbase + nt * 16 + lrow;
          ob[row * 144 + col] = f2bf(acc[mt][nt][r]);
        }
      }
    __syncthreads();
    // thread t: row = t>>2, quarter (t&3): 64B contiguous in row
    const u16* src = ob + (t >> 2) * 144 + (t & 3) * 32;
    u16* gdst = pws + ((size_t)hig * 1024 + (size_t)m * 128) * 128
                    + (t >> 2) * 128 + (t & 3) * 32;
#pragma unroll
    for (int i = 0; i < 4; ++i)
      *(s16x8*)(gdst + i * 8) = *(const s16x8*)(src + i * 8);
  }
}

// ---------------- reduce: out[e] = sum_hig P[hig][e] ----------------
__global__ __launch_bounds__(256) void k_reduce(
    const u16* __restrict__ p, float* __restrict__ out)
{
  const int g = blockIdx.x * 256 + threadIdx.x;   // 0..65535, 2 elems each
  const u16* src = p + (size_t)g * 2;
  float a0 = 0.0f, a1 = 0.0f;
#pragma unroll 8
  for (int hig = 0; hig < 64; ++hig) {
    uint32_t v = *(const uint32_t*)(src + (size_t)hig * 131072);
    a0 += __uint_as_float((v & 0xFFFFu) << 16);
    a1 += __uint_as_float(v & 0xFFFF0000u);
  }
  f32x2 o; o.x = a0; o.y = a1;
  *(f32x2*)(out + (size_t)g * 2) = o;
}

extern "C" void kernel_launch(void* const* d_in, const int* in_sizes, int n_in,
                              void* d_out, int out_size, void* d_ws, size_t ws_size,
                              hipStream_t stream)
{
  const float* x    = (const float*)d_in[0];
  const float* beta = (const float*)d_in[1];
  const float* cls  = (const float*)d_in[2];
  float* out = (float*)d_out;

  char* ws = (char*)d_ws;
  u16*   ct   = (u16*)ws;                               // 16,777,216 B
  u16*   plo  = (u16*)(ws + (16u << 20));               //    524,288 B
  float* phiT = (float*)(ws + (16u << 20) + 524288);    //  1,048,576 B
  u16*   pws  = (u16*)(ws + (16u << 20) + 524288 + 1048576); // 16,777,216 B

  k_tables<<<16, 256, 0, stream>>>(x, beta, plo, phiT);
  k_transpose<<<1024, 256, 0, stream>>>(cls, ct);
  k_main<<<512, 512, 0, stream>>>(plo, phiT, ct, pws);
  k_reduce<<<256, 256, 0, stream>>>(pws, out);
}

// Round 7
// 45.484 us; speedup vs baseline: 2.3116x; 1.1866x over previous
//
#include <hip/hip_runtime.h>
#include <stdint.h>

typedef unsigned short u16;
typedef __attribute__((ext_vector_type(4))) float f32x4;
typedef __attribute__((ext_vector_type(2))) float f32x2;
typedef __attribute__((ext_vector_type(8))) short s16x8;

#define T_INV 10.0f

__device__ __forceinline__ u16 f2bf(float f) {
  uint32_t u = __float_as_uint(f);
  uint32_t r = (u + 0x7FFFu + ((u >> 16) & 1u)) >> 16;
  return (u16)r;
}

__device__ __forceinline__ void gload_lds16(const void* g, void* l) {
  __builtin_amdgcn_global_load_lds(
      (const __attribute__((address_space(1))) uint32_t*)(g),
      (__attribute__((address_space(3))) uint32_t*)(l),
      16, 0, 0);
}

// ---------------- k_prep ----------------
// blocks 0..1023 : classifier fp32 [65536][128] -> bf16 CT3, fragment-major:
//                  element (k,c) at u16 offset (k>>3)*1024 + c*8 + (k&7)
// blocks 1024..1039 : per-row softmax tables
//                  plo[b][lo]  (bf16 [1024][256]),  phiT[hi][b] (f32 [256][1024])
__global__ __launch_bounds__(256) void k_prep(
    const float* __restrict__ cls, const float* __restrict__ x,
    const float* __restrict__ beta,
    u16* __restrict__ ct, u16* __restrict__ plo, float* __restrict__ phiT)
{
  const int t = threadIdx.x;
  if (blockIdx.x < 1024) {
    // ---- transpose ----
    __shared__ float tile[64 * 132];
    const int k0 = blockIdx.x * 64;
#pragma unroll
    for (int it = 0; it < 8; ++it) {
      int e = it * 1024 + t * 4;
      int r = e >> 7;
      int c = e & 127;
      f32x4 v = *(const f32x4*)(cls + (size_t)(k0 + r) * 128 + c);
      *(f32x4*)(tile + r * 132 + c) = v;
    }
    __syncthreads();
    const int c  = t >> 1;
    const int kh = t & 1;
    u16 vals[32];
#pragma unroll
    for (int j = 0; j < 32; ++j)
      vals[j] = f2bf(tile[(kh*32 + j) * 132 + c]);
    u16* dst = ct + ((size_t)(k0 >> 3) + kh * 4) * 1024 + c * 8;
#pragma unroll
    for (int qq = 0; qq < 4; ++qq) {
      s16x8 v;
#pragma unroll
      for (int e2 = 0; e2 < 8; ++e2) v[e2] = (short)vals[qq*8 + e2];
      *(s16x8*)(dst + (size_t)qq * 1024) = v;
    }
  } else {
    // ---- tables ----
    const int b = (blockIdx.x - 1024) * 64 + (t >> 2);
    const int q = t & 3;
    float hot[8][4];
#pragma unroll
    for (int f = 0; f < 8; ++f) {
      float b0 = beta[f*3+0], b1 = beta[f*3+1], b2 = beta[f*3+2];
      float s0 = fminf(b0, fminf(b1, b2));
      float s2 = fmaxf(b0, fmaxf(b1, b2));
      float s1 = b0 + b1 + b2 - s0 - s2;
      float bv1 = -s0, bv2 = -(s0 + s1), bv3 = -(s0 + s1 + s2);
      float xf = x[b*8 + f];
      float l0 = (xf * 1.0f       ) * T_INV;
      float l1 = (xf * 2.0f + bv1) * T_INV;
      float l2 = (xf * 3.0f + bv2) * T_INV;
      float l3 = (xf * 4.0f + bv3) * T_INV;
      float mm = fmaxf(fmaxf(l0, l1), fmaxf(l2, l3));
      float e0 = __expf(l0 - mm), e1 = __expf(l1 - mm);
      float e2 = __expf(l2 - mm), e3 = __expf(l3 - mm);
      float inv = 1.0f / (e0 + e1 + e2 + e3);
      hot[f][0] = e0*inv; hot[f][1] = e1*inv; hot[f][2] = e2*inv; hot[f][3] = e3*inv;
    }
    {
      float h23[16];
#pragma unroll
      for (int i2 = 0; i2 < 4; ++i2)
#pragma unroll
        for (int i3 = 0; i3 < 4; ++i3) h23[i2*4+i3] = hot[2][i2] * hot[3][i3];
      float h0q = hot[0][q];
#pragma unroll
      for (int i1 = 0; i1 < 4; ++i1) {
        float c01 = h0q * hot[1][i1];
#pragma unroll
        for (int j = 0; j < 16; ++j)
          phiT[(size_t)(q*64 + i1*16 + j) * 1024 + b] = c01 * h23[j];
      }
    }
    {
      float h67[16];
#pragma unroll
      for (int i6 = 0; i6 < 4; ++i6)
#pragma unroll
        for (int i7 = 0; i7 < 4; ++i7) h67[i6*4+i7] = hot[6][i6] * hot[7][i7];
      float h4q = hot[4][q];
      u16* dst = plo + (size_t)b*256 + q*64;
#pragma unroll
      for (int i5 = 0; i5 < 4; ++i5) {
        float c45 = h4q * hot[5][i5];
#pragma unroll
        for (int j = 0; j < 16; j += 8) {
          s16x8 v;
#pragma unroll
          for (int e = 0; e < 8; ++e) v[e] = (short)f2bf(c45 * h67[j+e]);
          *(s16x8*)(dst + i5*16 + j) = v;
        }
      }
    }
  }
}

// ---------------- main kernel ----------------
// grid 512 = 8 m-tiles (128 rows) x 64 hi-groups (4 his, K-chunk 1024)
// 256 threads / 4 waves; wave tile 64x64 (16 MFMA/step/wave)
// A (P_lo) static in 64KB LDS; B: depth-2 register pipeline from CT3
// (global->VGPR 2 steps ahead, ds_write 1 step ahead), ONE barrier/step.
__global__ __launch_bounds__(256, 2) void k_main(
    const u16* __restrict__ plo, const float* __restrict__ phiT,
    const u16* __restrict__ ct, u16* __restrict__ pws)
{
  __shared__ __align__(16) u16 As[32768];     // u16 idx: ks*4096 + row*32 + slot*8
  __shared__ __align__(16) u16 Bb[2][4096];   // [buf][col*32 + slot*8]

  const int wg  = blockIdx.x;
  const int xcd = wg & 7;
  const int idx = wg >> 3;
  const int hig = xcd * 8 + (idx >> 3);   // all 8 m-tiles of a hi-group on one XCD
  const int m   = idx & 7;

  const int t    = threadIdx.x;           // 0..255
  const int l    = t & 63;
  const int w    = t >> 6;                // 0..3
  const int lrow = l & 15;
  const int kg   = l >> 4;
  const int rbase = (w & 1) * 64;
  const int cbase = (w >> 1) * 64;

  const u16* ploM = plo + (size_t)m * 128 * 256;

  // ---- prologue: stage all of A (64KB) via global_load_lds ----
#pragma unroll
  for (int i = 0; i < 16; ++i) {
    int ks  = i >> 1;
    int row = (i & 1) * 64 + (t >> 2);
    int g   = ((t & 3) - ((t >> 3) & 3)) & 3;
    gload_lds16(ploM + (size_t)row * 256 + ks * 32 + g * 8, &As[i * 2048 + t * 8]);
  }

  // ---- B pipeline setup (CT3 fragment-major) ----
  const int bc = t & 127;            // col this thread stages
  const int bg = t >> 7;             // granule base: bg and bg+2
  const u16* bsrc = ct + (size_t)hig * 128 * 1024 + (size_t)bc * 8
                       + (size_t)bg * 1024;
  const int s0 = (bg + ((bc >> 1) & 3)) & 3;
  const int s2 = ((bg + 2) + ((bc >> 1) & 3)) & 3;

  s16x8 bregE0, bregE1, bregO0, bregO1;
  // loads for step 0 and step 1
  bregE0 = *(const s16x8*)(bsrc + 0 * 4096);
  bregE1 = *(const s16x8*)(bsrc + 0 * 4096 + 2048);
  bregO0 = *(const s16x8*)(bsrc + 1 * 4096);
  bregO1 = *(const s16x8*)(bsrc + 1 * 4096 + 2048);
  // write B(0) into Bb[0] (compiler waits bregE*, which also drains A stages)
  *(s16x8*)(&Bb[0][bc * 32 + s0 * 8]) = bregE0;
  *(s16x8*)(&Bb[0][bc * 32 + s2 * 8]) = bregE1;
  __syncthreads();

  f32x4 acc[4][4], hacc[4][4];
#pragma unroll
  for (int i = 0; i < 4; ++i)
#pragma unroll
    for (int j = 0; j < 4; ++j) { acc[i][j] = (f32x4)0.0f; hacc[i][j] = (f32x4)0.0f; }

#pragma unroll 1
  for (int h = 0; h < 4; ++h) {
#pragma unroll
    for (int ks = 0; ks < 8; ++ks) {
      const int tt = h * 8 + ks;
      // issue loads(tt+2) into slot[tt&1]
      if (h < 3 || ks < 6) {
        const u16* p = bsrc + (size_t)(tt + 2) * 4096;
        if (ks & 1) { bregO0 = *(const s16x8*)p; bregO1 = *(const s16x8*)(p + 2048); }
        else        { bregE0 = *(const s16x8*)p; bregE1 = *(const s16x8*)(p + 2048); }
      }
      // fragments + MFMA for step tt (buf = ks&1)
      s16x8 afr[4], bfr[4];
      const u16* Ak = &As[ks * 4096];
#pragma unroll
      for (int mt = 0; mt < 4; ++mt) {
        int row = rbase + mt * 16 + lrow;
        int s = (kg + ((row >> 1) & 3)) & 3;
        afr[mt] = *(const s16x8*)(Ak + row * 32 + s * 8);
      }
#pragma unroll
      for (int nt = 0; nt < 4; ++nt) {
        int c = cbase + nt * 16 + lrow;
        int s = (kg + ((c >> 1) & 3)) & 3;
        bfr[nt] = *(const s16x8*)(&Bb[ks & 1][c * 32 + s * 8]);
      }
#pragma unroll
      for (int mt = 0; mt < 4; ++mt)
#pragma unroll
        for (int nt = 0; nt < 4; ++nt)
          hacc[mt][nt] = __builtin_amdgcn_mfma_f32_16x16x32_bf16(
              afr[mt], bfr[nt], hacc[mt][nt], 0, 0, 0);
      // ds_write B(tt+1) from slot[(tt+1)&1] into Bb[(ks+1)&1]
      if (h < 3 || ks < 7) {
        u16* d = &Bb[(ks + 1) & 1][bc * 32];
        if (ks & 1) { *(s16x8*)(d + s0 * 8) = bregE0; *(s16x8*)(d + s2 * 8) = bregE1; }
        else        { *(s16x8*)(d + s0 * 8) = bregO0; *(s16x8*)(d + s2 * 8) = bregO1; }
      }
      asm volatile("s_waitcnt lgkmcnt(0)" ::: "memory");
      __builtin_amdgcn_sched_barrier(0);
      __builtin_amdgcn_s_barrier();
      __builtin_amdgcn_sched_barrier(0);
    }
    // fold hi h: acc += phiT[hig*4+h][m*128+row] * hacc
#pragma unroll
    for (int mt = 0; mt < 4; ++mt) {
      f32x4 p4 = *(const f32x4*)(phiT + (size_t)(hig * 4 + h) * 1024
                                 + m * 128 + rbase + mt * 16 + kg * 4);
#pragma unroll
      for (int r = 0; r < 4; ++r)
#pragma unroll
        for (int nt = 0; nt < 4; ++nt)
          acc[mt][nt][r] += p4[r] * hacc[mt][nt][r];
#pragma unroll
      for (int nt = 0; nt < 4; ++nt) hacc[mt][nt] = (f32x4)0.0f;
    }
  }

  // ---- epilogue: bounce through LDS (reuse As), coalesced 16B stores ----
  __syncthreads();
  {
    u16* ob = As;   // 128 rows x 136 u16 = 34816 B
#pragma unroll
    for (int mt = 0; mt < 4; ++mt)
#pragma unroll
      for (int r = 0; r < 4; ++r) {
        int row = rbase + mt * 16 + kg * 4 + r;
#pragma unroll
        for (int nt = 0; nt < 4; ++nt) {
          int col = cbase + nt * 16 + lrow;
          ob[row * 136 + col] = f2bf(acc[mt][nt][r]);
        }
      }
    __syncthreads();
    // thread t: row = t>>1, half = t&1, copy the FULL 64-u16 half-row
    const int row  = t >> 1;
    const int half = t & 1;
    const u16* srcp = ob + row * 136 + half * 64;
    u16* gdst = pws + ((size_t)hig * 1024 + (size_t)m * 128) * 128
                    + row * 128 + half * 64;
#pragma unroll
    for (int i = 0; i < 8; ++i)
      *(s16x8*)(gdst + i * 8) = *(const s16x8*)(srcp + i * 8);
  }
}

// ---------------- reduce: out[e] = sum_hig P[hig][e] ----------------
__global__ __launch_bounds__(256) void k_reduce(
    const u16* __restrict__ p, float* __restrict__ out)
{
  const int g = blockIdx.x * 256 + threadIdx.x;   // 0..65535, 2 elems each
  const u16* src = p + (size_t)g * 2;
  float a0 = 0.0f, a1 = 0.0f;
#pragma unroll 8
  for (int hig = 0; hig < 64; ++hig) {
    uint32_t v = *(const uint32_t*)(src + (size_t)hig * 131072);
    a0 += __uint_as_float((v & 0xFFFFu) << 16);
    a1 += __uint_as_float(v & 0xFFFF0000u);
  }
  f32x2 o; o.x = a0; o.y = a1;
  *(f32x2*)(out + (size_t)g * 2) = o;
}

extern "C" void kernel_launch(void* const* d_in, const int* in_sizes, int n_in,
                              void* d_out, int out_size, void* d_ws, size_t ws_size,
                              hipStream_t stream)
{
  const float* x    = (const float*)d_in[0];
  const float* beta = (const float*)d_in[1];
  const float* cls  = (const float*)d_in[2];
  float* out = (float*)d_out;

  char* ws = (char*)d_ws;
  u16*   ct   = (u16*)ws;                               // 16,777,216 B
  u16*   plo  = (u16*)(ws + (16u << 20));               //    524,288 B
  float* phiT = (float*)(ws + (16u << 20) + 524288);    //  1,048,576 B
  u16*   pws  = (u16*)(ws + (16u << 20) + 524288 + 1048576); // 16,777,216 B

  k_prep<<<1040, 256, 0, stream>>>(cls, x, beta, ct, plo, phiT);
  k_main<<<512, 256, 0, stream>>>(plo, phiT, ct, pws);
  k_reduce<<<256, 256, 0, stream>>>(pws, out);
}